// Round 8
// baseline (169.768 us; speedup 1.0000x reference)
//
#include <hip/hip_runtime.h>

namespace {

constexpr int Hh = 128, Ww = 128, HW = 128 * 128;
constexpr int Cin = 64, HID = 16, OC = 18;

typedef __attribute__((ext_vector_type(8))) short short8;
typedef __attribute__((ext_vector_type(4))) float f32x4;

__device__ __forceinline__ unsigned short f2bf(float f) {
  unsigned u = __builtin_bit_cast(unsigned, f);
  unsigned rounded = u + 0x7fffu + ((u >> 16) & 1u);
  return (unsigned short)(rounded >> 16);
}
__device__ __forceinline__ float bf2f(unsigned short s) {
  unsigned u = ((unsigned)s) << 16;
  return __builtin_bit_cast(float, u);
}

// ================= stage 1 (one launch, block-range split) =================
// blocks [0,512):    x NCHW fp32 -> xT [b][hw][c] bf16       (verified text)
// blocks [512,656):  w_out reorder -> wtb bf16 [oc][n*64+ic] (verified text)
// blocks [656,1168): fused offset branch -> offb [pix][18]   (verified math;
//                    halo now staged x->LDS with coalesced linear loads)
__global__ __launch_bounds__(256) void k_stage1(
    const float* __restrict__ x, const float* __restrict__ wout,
    const float* __restrict__ w1, const float* __restrict__ g1,
    const float* __restrict__ b1, const float* __restrict__ m1,
    const float* __restrict__ v1, const float* __restrict__ wdw,
    const float* __restrict__ g2, const float* __restrict__ b2,
    const float* __restrict__ m2, const float* __restrict__ v2,
    const float* __restrict__ w2, const float* __restrict__ g3,
    const float* __restrict__ b3, const float* __restrict__ m3,
    const float* __restrict__ v3, unsigned short* __restrict__ xT,
    unsigned short* __restrict__ wtb, float* __restrict__ offb) {
  __shared__ __align__(16) char smem[53664];
  const int blk = blockIdx.x;
  const int t = threadIdx.x;

  if (blk < 512) {  // ---- transpose to channel-last bf16 ----
    float(*T)[65] = (float(*)[65])smem;  // 16640 B
    const int b = blk >> 8;
    const int hw0 = (blk & 255) * 64;
    {
      const int p = t & 63, cg = t >> 6;
#pragma unroll
      for (int j = 0; j < 16; ++j) {
        const int c = cg * 16 + j;
        T[c][p] = x[(b * Cin + c) * HW + hw0 + p];
      }
    }
    __syncthreads();
    {
      const int c = t & 63, pg = t >> 6;
#pragma unroll
      for (int j = 0; j < 16; ++j) {
        const int p = pg * 16 + j;
        xT[((size_t)(b * HW + hw0 + p)) * 64 + c] = f2bf(T[c][p]);
      }
    }
    return;
  }
  if (blk < 656) {  // ---- weight reorder ----
    const int i = (blk - 512) * 256 + t;  // 36864 total
    const int oc = i / 576, r = i % 576;
    const int n = r >> 6, ic = r & 63;
    wtb[oc * 576 + r] = f2bf(wout[oc * 576 + ic * 9 + n]);
    return;
  }

  // ---- offset branch: tile 4x16, halo 6x18 = 108 px (round-6 geometry) ----
  const int blk2 = blk - 656;  // 0..511
  const int b = blk2 >> 8;
  const int r0 = ((blk2 >> 3) & 31) * 4;
  const int c0 = (blk2 & 7) * 16;
  float* xh = (float*)smem;                          // [64][108] = 27648 B
  float(*fpart)[HID][108] = (float(*)[HID][108])(smem + 27648);  // 13824 B
  float(*f)[108] = (float(*)[108])(smem + 41472);    // [16][108] = 6912 B
  float(*off2)[19] = (float(*)[19])(smem + 48384);   // [64][19] = 4864 B
  float* cst = (float*)(smem + 53248);               // 104 floats
  float* sA = cst;
  float* bA = cst + 16;
  float* sB = cst + 32;
  float* bB = cst + 50;
  float* sC = cst + 68;
  float* bC = cst + 86;

  if (t >= 192 && t < 208) {
    int o = t - 192;
    float inv = g1[o] * rsqrtf(v1[o] + 1e-5f);
    sA[o] = inv; bA[o] = b1[o] - m1[o] * inv;
  } else if (t >= 208 && t < 226) {
    int o = t - 208;
    float inv = g2[o] * rsqrtf(v2[o] + 1e-5f);
    sB[o] = inv; bB[o] = b2[o] - m2[o] * inv;
  } else if (t >= 226 && t < 244) {
    int o = t - 226;
    float inv = g3[o] * rsqrtf(v3[o] + 1e-5f);
    sC[o] = inv; bC[o] = b3[o] - m3[o] * inv;
  }

  // phase A-0: stage halo x -> LDS, linearized (coalesced within halo rows);
  // OOB pixels = 0 (conv2 zero-pad; A-1 sum over zeros = 0 as in verified ver)
  {
    const int base = b * Cin * HW;
    for (int i = t; i < 64 * 108; i += 256) {
      const int c = i / 108, px = i % 108;
      const int hp = r0 + px / 18 - 1;
      const int wp = c0 + (px % 18) - 1;
      float v = 0.f;
      if ((unsigned)hp < (unsigned)Hh && (unsigned)wp < (unsigned)Ww)
        v = x[base + c * HW + hp * Ww + wp];
      xh[c * 108 + px] = v;
    }
  }
  __syncthreads();

  // phase A-1: conv1 partial sums; item = (halo px, channel half)
  if (t < 216) {
    const int px = t % 108;  // halo pixel id, row-major 6x18
    const int cg = t / 108;  // channel half: 0 -> c 0..31, 1 -> c 32..63
    float acc[HID];
#pragma unroll
    for (int o = 0; o < HID; ++o) acc[o] = 0.f;
    for (int c = cg * 32; c < cg * 32 + 32; ++c) {
      const float xv = xh[c * 108 + px];
#pragma unroll
      for (int o = 0; o < HID; ++o)
        acc[o] = fmaf(w1[o * Cin + c], xv, acc[o]);
    }
#pragma unroll
    for (int o = 0; o < HID; ++o) fpart[cg][o][px] = acc[o];
  }
  __syncthreads();

  // phase A-2: reduce halves + BN + ReLU -> f (exact 0 outside image = pad)
  for (int idx = t; idx < 108 * HID; idx += 256) {
    const int px = idx % 108;
    const int o = idx / 108;
    const int hp = r0 + px / 18 - 1;
    const int wp = c0 + (px % 18) - 1;
    const float s = fpart[0][o][px] + fpart[1][o][px];
    const float y = fmaxf(fmaf(s, sA[o], bA[o]), 0.f);
    f[o][px] =
        ((unsigned)hp < (unsigned)Hh && (unsigned)wp < (unsigned)Ww) ? y : 0.f;
  }
  __syncthreads();

  // phase B: conv2(3x3) + BN + ReLU on threads <128 (verified semantics)
  if (t < 128) {
    const int ocg = t >> 6;
    const int px = t & 63;
    const int rr = px >> 4, cc = px & 15;
    float acc[9];
#pragma unroll
    for (int j = 0; j < 9; ++j) acc[j] = 0.f;
    for (int c = 0; c < HID; ++c) {
      float fv[9];
#pragma unroll
      for (int dh = 0; dh < 3; ++dh)
#pragma unroll
        for (int dw = 0; dw < 3; ++dw)
          fv[dh * 3 + dw] = f[c][(rr + dh) * 18 + cc + dw];
#pragma unroll
      for (int j = 0; j < 9; ++j) {
        const float* wj = wdw + (((ocg * 9 + j) * HID + c) * 9);
#pragma unroll
        for (int kk = 0; kk < 9; ++kk) acc[j] = fmaf(wj[kk], fv[kk], acc[j]);
      }
    }
#pragma unroll
    for (int j = 0; j < 9; ++j) {
      const int o = ocg * 9 + j;
      off2[px][o] = fmaxf(fmaf(acc[j], sB[o], bB[o]), 0.f);
    }
  }
  __syncthreads();

  // phase C: conv3(1x1) + BN + ReLU -> offb [pix][18] (verified semantics)
  if (t < 128) {
    const int ocg = t >> 6;
    const int px = t & 63;
    const int rr = px >> 4, cc = px & 15;
    float in[OC];
#pragma unroll
    for (int c = 0; c < OC; ++c) in[c] = off2[px][c];
    const int hw = (r0 + rr) * Ww + c0 + cc;
    float* dst = offb + ((size_t)(b * HW + hw)) * 18;
#pragma unroll
    for (int j = 0; j < 9; ++j) {
      const int o = ocg * 9 + j;
      float a = 0.f;
#pragma unroll
      for (int c = 0; c < OC; ++c) a = fmaf(w2[o * OC + c], in[c], a);
      dst[o] = fmaxf(fmaf(a, sC[o], bC[o]), 0.f);
    }
  }
}

// ---------------- fused gather + MFMA matmul + identity --------------------
// block = 16 consecutive pixels. 2048 blocks.  (verbatim verified)
__global__ __launch_bounds__(256) void k_main(
    const float* __restrict__ x, const unsigned short* __restrict__ xT,
    const float* __restrict__ offb, const unsigned short* __restrict__ wtb,
    float* __restrict__ out) {
  __shared__ unsigned short A[16][584];  // bf16, K' = n*64+ic
  __shared__ float sg[16][9][4];
  __shared__ int si[16][9][4];
  const int blk = blockIdx.x;
  const int b = blk >> 10;
  const int t = threadIdx.x;
  const int hw0 = (blk & 1023) * 16;

  // phase 0: per (pixel, sampling point): 4 corner pixel-indices + weights
  if (t < 144) {
    const int p = t / 9, n = t % 9;
    const int pix = blk * 16 + p;
    const int hw = pix & (HW - 1);
    const int h = hw >> 7, wc = hw & 127;
    const float offx = offb[pix * 18 + n];
    const float offy = offb[pix * 18 + 9 + n];
    const float px = (float)(h + (n / 3)) + offx;
    const float py = (float)(wc + (n % 3)) + offy;
    const float flx = floorf(px), fly = floorf(py);
    const float qltxf = fminf(fmaxf(flx, 0.f), 129.f);
    const float qltyf = fminf(fmaxf(fly, 0.f), 129.f);
    const float qrbxf = fminf(fmaxf(flx + 1.f, 0.f), 129.f);
    const float qrbyf = fminf(fmaxf(fly + 1.f, 0.f), 129.f);
    const float pxc = fminf(fmaxf(px, 0.f), 129.f);
    const float pyc = fminf(fmaxf(py, 0.f), 129.f);
    const float wx_lt = 1.f + (qltxf - pxc);
    const float wx_rb = 1.f - (qrbxf - pxc);
    const float wy_lt = 1.f + (qltyf - pyc);
    const float wy_rb = 1.f - (qrbyf - pyc);
    const int qltx = (int)qltxf, qlty = (int)qltyf;
    const int qrbx = (int)qrbxf, qrby = (int)qrbyf;
    const int cx[4] = {qltx, qrbx, qltx, qrbx};
    const int cy[4] = {qlty, qrby, qrby, qlty};
    const float gw[4] = {wx_lt * wy_lt, wx_rb * wy_rb, wx_lt * wy_rb,
                         wx_rb * wy_lt};
#pragma unroll
    for (int cc = 0; cc < 4; ++cc) {
      const bool valid =
          (cx[cc] >= 1) && (cx[cc] <= 128) && (cy[cc] >= 1) && (cy[cc] <= 128);
      si[p][n][cc] = valid ? ((cx[cc] - 1) * Ww + (cy[cc] - 1)) : 0;
      sg[p][n][cc] = valid ? gw[cc] : 0.f;
    }
  }
  __syncthreads();

  // phase 1: gather + blend -> A[pixel][n*64+ic]
  {
    const int p = t >> 4, ch4 = t & 15;
    const unsigned short* xb = xT + ((size_t)b * HW) * 64 + ch4 * 4;
#pragma unroll
    for (int n = 0; n < 9; ++n) {
      const ushort4 u0 = *(const ushort4*)(xb + (size_t)si[p][n][0] * 64);
      const ushort4 u1 = *(const ushort4*)(xb + (size_t)si[p][n][1] * 64);
      const ushort4 u2 = *(const ushort4*)(xb + (size_t)si[p][n][2] * 64);
      const ushort4 u3 = *(const ushort4*)(xb + (size_t)si[p][n][3] * 64);
      const float g0 = sg[p][n][0], g1 = sg[p][n][1], g2 = sg[p][n][2],
                  g3 = sg[p][n][3];
      float r0 = g0 * bf2f(u0.x);
      float r1 = g0 * bf2f(u0.y);
      float r2 = g0 * bf2f(u0.z);
      float r3 = g0 * bf2f(u0.w);
      r0 = fmaf(g1, bf2f(u1.x), r0); r1 = fmaf(g1, bf2f(u1.y), r1);
      r2 = fmaf(g1, bf2f(u1.z), r2); r3 = fmaf(g1, bf2f(u1.w), r3);
      r0 = fmaf(g2, bf2f(u2.x), r0); r1 = fmaf(g2, bf2f(u2.y), r1);
      r2 = fmaf(g2, bf2f(u2.z), r2); r3 = fmaf(g2, bf2f(u2.w), r3);
      r0 = fmaf(g3, bf2f(u3.x), r0); r1 = fmaf(g3, bf2f(u3.y), r1);
      r2 = fmaf(g3, bf2f(u3.z), r2); r3 = fmaf(g3, bf2f(u3.w), r3);
      ushort4 o;
      o.x = f2bf(r0); o.y = f2bf(r1); o.z = f2bf(r2); o.w = f2bf(r3);
      *(ushort4*)&A[p][n * 64 + ch4 * 4] = o;
    }
  }
  __syncthreads();

  // phase 2: MFMA. D[oc 16][pixel 16] per wave.
  {
    const int wv = t >> 6;
    const int lane = t & 63;
    const int l15 = lane & 15;
    const int quad = lane >> 4;
    const unsigned short* wrow = wtb + (size_t)(wv * 16 + l15) * 576 + quad * 8;
    const unsigned short* arow = &A[l15][quad * 8];
    f32x4 acc = {0.f, 0.f, 0.f, 0.f};
#pragma unroll
    for (int kb = 0; kb < 18; ++kb) {
      short8 af = *(const short8*)(wrow + kb * 32);
      short8 bf = *(const short8*)(arow + kb * 32);
      acc = __builtin_amdgcn_mfma_f32_16x16x32_bf16(af, bf, acc, 0, 0, 0);
    }
#pragma unroll
    for (int r = 0; r < 4; ++r) {
      const int oc = wv * 16 + quad * 4 + r;
      const size_t idx = ((size_t)(b * Cin + oc)) * HW + hw0 + l15;
      out[idx] = x[idx] + acc[r];
    }
  }
}

}  // namespace

extern "C" void kernel_launch(void* const* d_in, const int* in_sizes, int n_in,
                              void* d_out, int out_size, void* d_ws,
                              size_t ws_size, hipStream_t stream) {
  const float* x = (const float*)d_in[0];
  const float* w1 = (const float*)d_in[1];
  const float* g1 = (const float*)d_in[2];
  const float* b1 = (const float*)d_in[3];
  const float* m1 = (const float*)d_in[4];
  const float* v1 = (const float*)d_in[5];
  const float* wdw = (const float*)d_in[6];
  const float* g2 = (const float*)d_in[7];
  const float* b2 = (const float*)d_in[8];
  const float* m2 = (const float*)d_in[9];
  const float* v2 = (const float*)d_in[10];
  const float* w2 = (const float*)d_in[11];
  const float* g3 = (const float*)d_in[12];
  const float* b3 = (const float*)d_in[13];
  const float* m3 = (const float*)d_in[14];
  const float* v3 = (const float*)d_in[15];
  const float* wout = (const float*)d_in[16];
  float* out = (float*)d_out;

  char* ws = (char*)d_ws;
  unsigned short* wtb = (unsigned short*)ws;           // 73,728 B (pad 81920)
  unsigned short* xT = (unsigned short*)(ws + 81920);  // 4,194,304 B
  float* offb = (float*)(ws + 81920 + 4194304);        // 2,359,296 B

  k_stage1<<<1168, 256, 0, stream>>>(x, wout, w1, g1, b1, m1, v1, wdw, g2, b2,
                                     m2, v2, w2, g3, b3, m3, v3, xT, wtb,
                                     offb);
  k_main<<<2048, 256, 0, stream>>>(x, xT, offb, wtb, out);
}

// Round 9
// 136.658 us; speedup vs baseline: 1.2423x; 1.2423x over previous
//
#include <hip/hip_runtime.h>

namespace {

constexpr int Hh = 128, Ww = 128, HW = 128 * 128;
constexpr int Cin = 64, HID = 16, OC = 18;

typedef __attribute__((ext_vector_type(8))) short short8;
typedef __attribute__((ext_vector_type(4))) float f32x4;

__device__ __forceinline__ unsigned short f2bf(float f) {
  unsigned u = __builtin_bit_cast(unsigned, f);
  unsigned rounded = u + 0x7fffu + ((u >> 16) & 1u);
  return (unsigned short)(rounded >> 16);
}
__device__ __forceinline__ float bf2f(unsigned short s) {
  unsigned u = ((unsigned)s) << 16;
  return __builtin_bit_cast(float, u);
}

// ---------------- pre: x transpose to channel-last (bf16 + fp32) + w reorder
// blocks [0,512): xT/xTf;  blocks [512,656): wtb2 (MFMA-fragment order)
__global__ __launch_bounds__(256) void k_pre(const float* __restrict__ x,
                                             unsigned short* __restrict__ xT,
                                             float* __restrict__ xTf,
                                             const float* __restrict__ w,
                                             unsigned short* __restrict__ wtb) {
  __shared__ float T[64][65];
  const int blk = blockIdx.x;
  const int t = threadIdx.x;
  if (blk >= 512) {
    // w_out [oc][ic*9+n] fp32 -> wtb2 bf16 in MFMA A-fragment order:
    // k = n*64+ic; kb=k>>5; quad=(k>>3)&3; j=k&7; wv=oc>>4; l15=oc&15
    // idx2 = ((wv*18+kb)*64 + quad*16 + l15)*8 + j
    const int i = (blk - 512) * 256 + t;  // 36864 total, source-major
    const int oc = i / 576, r = i % 576;
    const int ic = r / 9, n = r % 9;
    const int k = n * 64 + ic;
    const int kb = k >> 5, quad = (k >> 3) & 3, j = k & 7;
    const int wv = oc >> 4, l15 = oc & 15;
    wtb[(((wv * 18 + kb) * 64 + quad * 16 + l15) << 3) + j] = f2bf(w[i]);
    return;
  }
  const int b = blk >> 8;
  const int hw0 = (blk & 255) * 64;
  {
    const int p = t & 63, cg = t >> 6;
#pragma unroll
    for (int j = 0; j < 16; ++j) {
      const int c = cg * 16 + j;
      T[c][p] = x[(b * Cin + c) * HW + hw0 + p];
    }
  }
  __syncthreads();
  {
    const int c = t & 63, pg = t >> 6;
#pragma unroll
    for (int j = 0; j < 16; ++j) {
      const int p = pg * 16 + j;
      const float val = T[c][p];
      const size_t base = ((size_t)(b * HW + hw0 + p)) * 64 + c;
      xT[base] = f2bf(val);
      xTf[base] = val;
    }
  }
}

// ---------------- fused offset branch (verbatim round-7 verified) ----------
__global__ __launch_bounds__(256) void k_off(
    const float* __restrict__ xTf, const float* __restrict__ w1,
    const float* __restrict__ g1, const float* __restrict__ b1,
    const float* __restrict__ m1, const float* __restrict__ v1,
    const float* __restrict__ wdw, const float* __restrict__ g2,
    const float* __restrict__ b2, const float* __restrict__ m2,
    const float* __restrict__ v2, const float* __restrict__ w2,
    const float* __restrict__ g3, const float* __restrict__ b3,
    const float* __restrict__ m3, const float* __restrict__ v3,
    float* __restrict__ offb) {
  __shared__ float fpart[2][HID][108];
  __shared__ float f[HID][108];
  __shared__ float off2[64][19];
  __shared__ float sA[16], bA[16], sB[18], bB[18], sC[18], bC[18];
  const int t = threadIdx.x;
  const int blk = blockIdx.x;
  const int b = blk >> 8;
  const int r0 = ((blk >> 3) & 31) * 4;
  const int c0 = (blk & 7) * 16;

  if (t >= 192 && t < 208) {
    int o = t - 192;
    float inv = g1[o] * rsqrtf(v1[o] + 1e-5f);
    sA[o] = inv; bA[o] = b1[o] - m1[o] * inv;
  } else if (t >= 208 && t < 226) {
    int o = t - 208;
    float inv = g2[o] * rsqrtf(v2[o] + 1e-5f);
    sB[o] = inv; bB[o] = b2[o] - m2[o] * inv;
  } else if (t >= 226 && t < 244) {
    int o = t - 226;
    float inv = g3[o] * rsqrtf(v3[o] + 1e-5f);
    sC[o] = inv; bC[o] = b3[o] - m3[o] * inv;
  }

  if (t < 216) {
    const int px = t % 108;
    const int cg = t / 108;
    const int hp = r0 + px / 18 - 1;
    const int wp = c0 + (px % 18) - 1;
    float acc[HID];
#pragma unroll
    for (int o = 0; o < HID; ++o) acc[o] = 0.f;
    if ((unsigned)hp < (unsigned)Hh && (unsigned)wp < (unsigned)Ww) {
      const float* xp = xTf + ((size_t)(b * HW + hp * Ww + wp)) * 64 + cg * 32;
#pragma unroll
      for (int c4 = 0; c4 < 8; ++c4) {
        const float4 xv = *(const float4*)(xp + c4 * 4);
        const int c = cg * 32 + c4 * 4;
#pragma unroll
        for (int o = 0; o < HID; ++o)
          acc[o] = fmaf(w1[o * Cin + c], xv.x, acc[o]);
#pragma unroll
        for (int o = 0; o < HID; ++o)
          acc[o] = fmaf(w1[o * Cin + c + 1], xv.y, acc[o]);
#pragma unroll
        for (int o = 0; o < HID; ++o)
          acc[o] = fmaf(w1[o * Cin + c + 2], xv.z, acc[o]);
#pragma unroll
        for (int o = 0; o < HID; ++o)
          acc[o] = fmaf(w1[o * Cin + c + 3], xv.w, acc[o]);
      }
    }
#pragma unroll
    for (int o = 0; o < HID; ++o) fpart[cg][o][px] = acc[o];
  }
  __syncthreads();

  for (int idx = t; idx < 108 * HID; idx += 256) {
    const int px = idx % 108;
    const int o = idx / 108;
    const int hp = r0 + px / 18 - 1;
    const int wp = c0 + (px % 18) - 1;
    const float s = fpart[0][o][px] + fpart[1][o][px];
    const float y = fmaxf(fmaf(s, sA[o], bA[o]), 0.f);
    f[o][px] =
        ((unsigned)hp < (unsigned)Hh && (unsigned)wp < (unsigned)Ww) ? y : 0.f;
  }
  __syncthreads();

  if (t < 128) {
    const int ocg = t >> 6;
    const int px = t & 63;
    const int rr = px >> 4, cc = px & 15;
    float acc[9];
#pragma unroll
    for (int j = 0; j < 9; ++j) acc[j] = 0.f;
    for (int c = 0; c < HID; ++c) {
      float fv[9];
#pragma unroll
      for (int dh = 0; dh < 3; ++dh)
#pragma unroll
        for (int dw = 0; dw < 3; ++dw)
          fv[dh * 3 + dw] = f[c][(rr + dh) * 18 + cc + dw];
#pragma unroll
      for (int j = 0; j < 9; ++j) {
        const float* wj = wdw + (((ocg * 9 + j) * HID + c) * 9);
#pragma unroll
        for (int kk = 0; kk < 9; ++kk) acc[j] = fmaf(wj[kk], fv[kk], acc[j]);
      }
    }
#pragma unroll
    for (int j = 0; j < 9; ++j) {
      const int o = ocg * 9 + j;
      off2[px][o] = fmaxf(fmaf(acc[j], sB[o], bB[o]), 0.f);
    }
  }
  __syncthreads();

  if (t < 128) {
    const int ocg = t >> 6;
    const int px = t & 63;
    const int rr = px >> 4, cc = px & 15;
    float in[OC];
#pragma unroll
    for (int c = 0; c < OC; ++c) in[c] = off2[px][c];
    const int hw = (r0 + rr) * Ww + c0 + cc;
    float* dst = offb + ((size_t)(b * HW + hw)) * 18;
#pragma unroll
    for (int j = 0; j < 9; ++j) {
      const int o = ocg * 9 + j;
      float a = 0.f;
#pragma unroll
      for (int c = 0; c < OC; ++c) a = fmaf(w2[o * OC + c], in[c], a);
      dst[o] = fmaxf(fmaf(a, sC[o], bC[o]), 0.f);
    }
  }
}

// ---------------- fused gather + MFMA matmul + identity --------------------
// block = 16 consecutive pixels. 2048 blocks.
// (round-7 verified text; only the wtb pointer arithmetic changed)
__global__ __launch_bounds__(256) void k_main(
    const float* __restrict__ x, const unsigned short* __restrict__ xT,
    const float* __restrict__ offb, const unsigned short* __restrict__ wtb,
    float* __restrict__ out) {
  __shared__ unsigned short A[16][584];
  __shared__ float sg[16][9][4];
  __shared__ int si[16][9][4];
  const int blk = blockIdx.x;
  const int b = blk >> 10;
  const int t = threadIdx.x;
  const int hw0 = (blk & 1023) * 16;

  if (t < 144) {
    const int p = t / 9, n = t % 9;
    const int pix = blk * 16 + p;
    const int hw = pix & (HW - 1);
    const int h = hw >> 7, wc = hw & 127;
    const float offx = offb[pix * 18 + n];
    const float offy = offb[pix * 18 + 9 + n];
    const float px = (float)(h + (n / 3)) + offx;
    const float py = (float)(wc + (n % 3)) + offy;
    const float flx = floorf(px), fly = floorf(py);
    const float qltxf = fminf(fmaxf(flx, 0.f), 129.f);
    const float qltyf = fminf(fmaxf(fly, 0.f), 129.f);
    const float qrbxf = fminf(fmaxf(flx + 1.f, 0.f), 129.f);
    const float qrbyf = fminf(fmaxf(fly + 1.f, 0.f), 129.f);
    const float pxc = fminf(fmaxf(px, 0.f), 129.f);
    const float pyc = fminf(fmaxf(py, 0.f), 129.f);
    const float wx_lt = 1.f + (qltxf - pxc);
    const float wx_rb = 1.f - (qrbxf - pxc);
    const float wy_lt = 1.f + (qltyf - pyc);
    const float wy_rb = 1.f - (qrbyf - pyc);
    const int qltx = (int)qltxf, qlty = (int)qltyf;
    const int qrbx = (int)qrbxf, qrby = (int)qrbyf;
    const int cx[4] = {qltx, qrbx, qltx, qrbx};
    const int cy[4] = {qlty, qrby, qrby, qlty};
    const float gw[4] = {wx_lt * wy_lt, wx_rb * wy_rb, wx_lt * wy_rb,
                         wx_rb * wy_lt};
#pragma unroll
    for (int cc = 0; cc < 4; ++cc) {
      const bool valid =
          (cx[cc] >= 1) && (cx[cc] <= 128) && (cy[cc] >= 1) && (cy[cc] <= 128);
      si[p][n][cc] = valid ? ((cx[cc] - 1) * Ww + (cy[cc] - 1)) : 0;
      sg[p][n][cc] = valid ? gw[cc] : 0.f;
    }
  }
  __syncthreads();

  {
    const int p = t >> 4, ch4 = t & 15;
    const unsigned short* xb = xT + ((size_t)b * HW) * 64 + ch4 * 4;
#pragma unroll
    for (int n = 0; n < 9; ++n) {
      const ushort4 u0 = *(const ushort4*)(xb + (size_t)si[p][n][0] * 64);
      const ushort4 u1 = *(const ushort4*)(xb + (size_t)si[p][n][1] * 64);
      const ushort4 u2 = *(const ushort4*)(xb + (size_t)si[p][n][2] * 64);
      const ushort4 u3 = *(const ushort4*)(xb + (size_t)si[p][n][3] * 64);
      const float g0 = sg[p][n][0], g1 = sg[p][n][1], g2 = sg[p][n][2],
                  g3 = sg[p][n][3];
      float r0 = g0 * bf2f(u0.x);
      float r1 = g0 * bf2f(u0.y);
      float r2 = g0 * bf2f(u0.z);
      float r3 = g0 * bf2f(u0.w);
      r0 = fmaf(g1, bf2f(u1.x), r0); r1 = fmaf(g1, bf2f(u1.y), r1);
      r2 = fmaf(g1, bf2f(u1.z), r2); r3 = fmaf(g1, bf2f(u1.w), r3);
      r0 = fmaf(g2, bf2f(u2.x), r0); r1 = fmaf(g2, bf2f(u2.y), r1);
      r2 = fmaf(g2, bf2f(u2.z), r2); r3 = fmaf(g2, bf2f(u2.w), r3);
      r0 = fmaf(g3, bf2f(u3.x), r0); r1 = fmaf(g3, bf2f(u3.y), r1);
      r2 = fmaf(g3, bf2f(u3.z), r2); r3 = fmaf(g3, bf2f(u3.w), r3);
      ushort4 o;
      o.x = f2bf(r0); o.y = f2bf(r1); o.z = f2bf(r2); o.w = f2bf(r3);
      *(ushort4*)&A[p][n * 64 + ch4 * 4] = o;
    }
  }
  __syncthreads();

  // phase 2: MFMA. wtb2 fragment-order: instr reads 64 lanes x 16 B contig.
  {
    const int wv = t >> 6;
    const int lane = t & 63;
    const int l15 = lane & 15;
    const int quad = lane >> 4;
    const unsigned short* wbase = wtb + (((size_t)wv * 18) * 64 + lane) * 8;
    const unsigned short* arow = &A[l15][quad * 8];
    f32x4 acc = {0.f, 0.f, 0.f, 0.f};
#pragma unroll
    for (int kb = 0; kb < 18; ++kb) {
      short8 af = *(const short8*)(wbase + kb * 512);
      short8 bf = *(const short8*)(arow + kb * 32);
      acc = __builtin_amdgcn_mfma_f32_16x16x32_bf16(af, bf, acc, 0, 0, 0);
    }
#pragma unroll
    for (int r = 0; r < 4; ++r) {
      const int oc = wv * 16 + quad * 4 + r;
      const size_t idx = ((size_t)(b * Cin + oc)) * HW + hw0 + l15;
      out[idx] = x[idx] + acc[r];
    }
  }
}

}  // namespace

extern "C" void kernel_launch(void* const* d_in, const int* in_sizes, int n_in,
                              void* d_out, int out_size, void* d_ws,
                              size_t ws_size, hipStream_t stream) {
  const float* x = (const float*)d_in[0];
  const float* w1 = (const float*)d_in[1];
  const float* g1 = (const float*)d_in[2];
  const float* b1 = (const float*)d_in[3];
  const float* m1 = (const float*)d_in[4];
  const float* v1 = (const float*)d_in[5];
  const float* wdw = (const float*)d_in[6];
  const float* g2 = (const float*)d_in[7];
  const float* b2 = (const float*)d_in[8];
  const float* m2 = (const float*)d_in[9];
  const float* v2 = (const float*)d_in[10];
  const float* w2 = (const float*)d_in[11];
  const float* g3 = (const float*)d_in[12];
  const float* b3 = (const float*)d_in[13];
  const float* m3 = (const float*)d_in[14];
  const float* v3 = (const float*)d_in[15];
  const float* wout = (const float*)d_in[16];
  float* out = (float*)d_out;

  char* ws = (char*)d_ws;
  unsigned short* wtb = (unsigned short*)ws;           // 73,728 B (pad 81920)
  unsigned short* xT = (unsigned short*)(ws + 81920);  // 4,194,304 B
  float* offb = (float*)(ws + 81920 + 4194304);        // 2,359,296 B
  float* xTf = (float*)(ws + 81920 + 4194304 + 2359296);  // 8,388,608 B

  k_pre<<<656, 256, 0, stream>>>(x, xT, xTf, wout, wtb);
  k_off<<<512, 256, 0, stream>>>(xTf, w1, g1, b1, m1, v1, wdw, g2, b2, m2, v2,
                                 w2, g3, b3, m3, v3, offb);
  k_main<<<2048, 256, 0, stream>>>(x, xT, offb, wtb, out);
}

// Round 10
// 134.364 us; speedup vs baseline: 1.2635x; 1.0171x over previous
//
#include <hip/hip_runtime.h>

namespace {

constexpr int Hh = 128, Ww = 128, HW = 128 * 128;
constexpr int Cin = 64, HID = 16, OC = 18;

typedef __attribute__((ext_vector_type(8))) short short8;
typedef __attribute__((ext_vector_type(4))) float f32x4;

__device__ __forceinline__ unsigned short f2bf(float f) {
  unsigned u = __builtin_bit_cast(unsigned, f);
  unsigned rounded = u + 0x7fffu + ((u >> 16) & 1u);
  return (unsigned short)(rounded >> 16);
}
__device__ __forceinline__ float bf2f(unsigned short s) {
  unsigned u = ((unsigned)s) << 16;
  return __builtin_bit_cast(float, u);
}

// ---------------- pre: x transpose to channel-last bf16 + w reorder --------
// blocks [0,512): xT;  blocks [512,656): wtb2 (MFMA-fragment order, verified)
__global__ __launch_bounds__(256) void k_pre(const float* __restrict__ x,
                                             unsigned short* __restrict__ xT,
                                             const float* __restrict__ w,
                                             unsigned short* __restrict__ wtb) {
  __shared__ float T[64][65];
  const int blk = blockIdx.x;
  const int t = threadIdx.x;
  if (blk >= 512) {
    // w_out [oc][ic*9+n] fp32 -> wtb2 bf16 in MFMA A-fragment order:
    // k = n*64+ic; kb=k>>5; quad=(k>>3)&3; j=k&7; wv=oc>>4; l15=oc&15
    const int i = (blk - 512) * 256 + t;  // 36864 total, source-major
    const int oc = i / 576, r = i % 576;
    const int ic = r / 9, n = r % 9;
    const int k = n * 64 + ic;
    const int kb = k >> 5, quad = (k >> 3) & 3, j = k & 7;
    const int wv = oc >> 4, l15 = oc & 15;
    wtb[(((wv * 18 + kb) * 64 + quad * 16 + l15) << 3) + j] = f2bf(w[i]);
    return;
  }
  const int b = blk >> 8;
  const int hw0 = (blk & 255) * 64;
  {
    const int p = t & 63, cg = t >> 6;
#pragma unroll
    for (int j = 0; j < 16; ++j) {
      const int c = cg * 16 + j;
      T[c][p] = x[(b * Cin + c) * HW + hw0 + p];
    }
  }
  __syncthreads();
  {
    const int c = t & 63, pg = t >> 6;
#pragma unroll
    for (int j = 0; j < 16; ++j) {
      const int p = pg * 16 + j;
      xT[((size_t)(b * HW + hw0 + p)) * 64 + c] = f2bf(T[c][p]);
    }
  }
}

// ---------------- fused offset branch (round-7 verified structure) ---------
// Phase A now reads the bf16 xT (half the bytes of the old fp32 shadow).
__global__ __launch_bounds__(256) void k_off(
    const unsigned short* __restrict__ xT, const float* __restrict__ w1,
    const float* __restrict__ g1, const float* __restrict__ b1,
    const float* __restrict__ m1, const float* __restrict__ v1,
    const float* __restrict__ wdw, const float* __restrict__ g2,
    const float* __restrict__ b2, const float* __restrict__ m2,
    const float* __restrict__ v2, const float* __restrict__ w2,
    const float* __restrict__ g3, const float* __restrict__ b3,
    const float* __restrict__ m3, const float* __restrict__ v3,
    float* __restrict__ offb) {
  __shared__ float fpart[2][HID][108];
  __shared__ float f[HID][108];
  __shared__ float off2[64][19];
  __shared__ float sA[16], bA[16], sB[18], bB[18], sC[18], bC[18];
  const int t = threadIdx.x;
  const int blk = blockIdx.x;
  const int b = blk >> 8;
  const int r0 = ((blk >> 3) & 31) * 4;
  const int c0 = (blk & 7) * 16;

  if (t >= 192 && t < 208) {
    int o = t - 192;
    float inv = g1[o] * rsqrtf(v1[o] + 1e-5f);
    sA[o] = inv; bA[o] = b1[o] - m1[o] * inv;
  } else if (t >= 208 && t < 226) {
    int o = t - 208;
    float inv = g2[o] * rsqrtf(v2[o] + 1e-5f);
    sB[o] = inv; bB[o] = b2[o] - m2[o] * inv;
  } else if (t >= 226 && t < 244) {
    int o = t - 226;
    float inv = g3[o] * rsqrtf(v3[o] + 1e-5f);
    sC[o] = inv; bC[o] = b3[o] - m3[o] * inv;
  }

  // phase A-1: conv1 partial sums; item = (halo px, channel half)
  if (t < 216) {
    const int px = t % 108;
    const int cg = t / 108;
    const int hp = r0 + px / 18 - 1;
    const int wp = c0 + (px % 18) - 1;
    float acc[HID];
#pragma unroll
    for (int o = 0; o < HID; ++o) acc[o] = 0.f;
    if ((unsigned)hp < (unsigned)Hh && (unsigned)wp < (unsigned)Ww) {
      const unsigned short* xp =
          xT + ((size_t)(b * HW + hp * Ww + wp)) * 64 + cg * 32;
#pragma unroll
      for (int c4 = 0; c4 < 8; ++c4) {
        const ushort4 xv = *(const ushort4*)(xp + c4 * 4);
        const float x0 = bf2f(xv.x), x1 = bf2f(xv.y), x2 = bf2f(xv.z),
                    x3 = bf2f(xv.w);
        const int c = cg * 32 + c4 * 4;
#pragma unroll
        for (int o = 0; o < HID; ++o)
          acc[o] = fmaf(w1[o * Cin + c], x0, acc[o]);
#pragma unroll
        for (int o = 0; o < HID; ++o)
          acc[o] = fmaf(w1[o * Cin + c + 1], x1, acc[o]);
#pragma unroll
        for (int o = 0; o < HID; ++o)
          acc[o] = fmaf(w1[o * Cin + c + 2], x2, acc[o]);
#pragma unroll
        for (int o = 0; o < HID; ++o)
          acc[o] = fmaf(w1[o * Cin + c + 3], x3, acc[o]);
      }
    }
#pragma unroll
    for (int o = 0; o < HID; ++o) fpart[cg][o][px] = acc[o];
  }
  __syncthreads();

  // phase A-2: reduce halves + BN + ReLU -> f (exact 0 outside image = pad)
  for (int idx = t; idx < 108 * HID; idx += 256) {
    const int px = idx % 108;
    const int o = idx / 108;
    const int hp = r0 + px / 18 - 1;
    const int wp = c0 + (px % 18) - 1;
    const float s = fpart[0][o][px] + fpart[1][o][px];
    const float y = fmaxf(fmaf(s, sA[o], bA[o]), 0.f);
    f[o][px] =
        ((unsigned)hp < (unsigned)Hh && (unsigned)wp < (unsigned)Ww) ? y : 0.f;
  }
  __syncthreads();

  // phase B: conv2(3x3) + BN + ReLU on threads <128 (verified semantics)
  if (t < 128) {
    const int ocg = t >> 6;
    const int px = t & 63;
    const int rr = px >> 4, cc = px & 15;
    float acc[9];
#pragma unroll
    for (int j = 0; j < 9; ++j) acc[j] = 0.f;
    for (int c = 0; c < HID; ++c) {
      float fv[9];
#pragma unroll
      for (int dh = 0; dh < 3; ++dh)
#pragma unroll
        for (int dw = 0; dw < 3; ++dw)
          fv[dh * 3 + dw] = f[c][(rr + dh) * 18 + cc + dw];
#pragma unroll
      for (int j = 0; j < 9; ++j) {
        const float* wj = wdw + (((ocg * 9 + j) * HID + c) * 9);
#pragma unroll
        for (int kk = 0; kk < 9; ++kk) acc[j] = fmaf(wj[kk], fv[kk], acc[j]);
      }
    }
#pragma unroll
    for (int j = 0; j < 9; ++j) {
      const int o = ocg * 9 + j;
      off2[px][o] = fmaxf(fmaf(acc[j], sB[o], bB[o]), 0.f);
    }
  }
  __syncthreads();

  // phase C: conv3(1x1) + BN + ReLU -> offb [pix][18] (verified semantics)
  if (t < 128) {
    const int ocg = t >> 6;
    const int px = t & 63;
    const int rr = px >> 4, cc = px & 15;
    float in[OC];
#pragma unroll
    for (int c = 0; c < OC; ++c) in[c] = off2[px][c];
    const int hw = (r0 + rr) * Ww + c0 + cc;
    float* dst = offb + ((size_t)(b * HW + hw)) * 18;
#pragma unroll
    for (int j = 0; j < 9; ++j) {
      const int o = ocg * 9 + j;
      float a = 0.f;
#pragma unroll
      for (int c = 0; c < OC; ++c) a = fmaf(w2[o * OC + c], in[c], a);
      dst[o] = fmaxf(fmaf(a, sC[o], bC[o]), 0.f);
    }
  }
}

// ---------------- fused gather + MFMA matmul + identity --------------------
// block = 16 consecutive pixels. 2048 blocks.  (verbatim round-9 verified)
__global__ __launch_bounds__(256) void k_main(
    const float* __restrict__ x, const unsigned short* __restrict__ xT,
    const float* __restrict__ offb, const unsigned short* __restrict__ wtb,
    float* __restrict__ out) {
  __shared__ unsigned short A[16][584];
  __shared__ float sg[16][9][4];
  __shared__ int si[16][9][4];
  const int blk = blockIdx.x;
  const int b = blk >> 10;
  const int t = threadIdx.x;
  const int hw0 = (blk & 1023) * 16;

  if (t < 144) {
    const int p = t / 9, n = t % 9;
    const int pix = blk * 16 + p;
    const int hw = pix & (HW - 1);
    const int h = hw >> 7, wc = hw & 127;
    const float offx = offb[pix * 18 + n];
    const float offy = offb[pix * 18 + 9 + n];
    const float px = (float)(h + (n / 3)) + offx;
    const float py = (float)(wc + (n % 3)) + offy;
    const float flx = floorf(px), fly = floorf(py);
    const float qltxf = fminf(fmaxf(flx, 0.f), 129.f);
    const float qltyf = fminf(fmaxf(fly, 0.f), 129.f);
    const float qrbxf = fminf(fmaxf(flx + 1.f, 0.f), 129.f);
    const float qrbyf = fminf(fmaxf(fly + 1.f, 0.f), 129.f);
    const float pxc = fminf(fmaxf(px, 0.f), 129.f);
    const float pyc = fminf(fmaxf(py, 0.f), 129.f);
    const float wx_lt = 1.f + (qltxf - pxc);
    const float wx_rb = 1.f - (qrbxf - pxc);
    const float wy_lt = 1.f + (qltyf - pyc);
    const float wy_rb = 1.f - (qrbyf - pyc);
    const int qltx = (int)qltxf, qlty = (int)qltyf;
    const int qrbx = (int)qrbxf, qrby = (int)qrbyf;
    const int cx[4] = {qltx, qrbx, qltx, qrbx};
    const int cy[4] = {qlty, qrby, qrby, qlty};
    const float gw[4] = {wx_lt * wy_lt, wx_rb * wy_rb, wx_lt * wy_rb,
                         wx_rb * wy_lt};
#pragma unroll
    for (int cc = 0; cc < 4; ++cc) {
      const bool valid =
          (cx[cc] >= 1) && (cx[cc] <= 128) && (cy[cc] >= 1) && (cy[cc] <= 128);
      si[p][n][cc] = valid ? ((cx[cc] - 1) * Ww + (cy[cc] - 1)) : 0;
      sg[p][n][cc] = valid ? gw[cc] : 0.f;
    }
  }
  __syncthreads();

  {
    const int p = t >> 4, ch4 = t & 15;
    const unsigned short* xb = xT + ((size_t)b * HW) * 64 + ch4 * 4;
#pragma unroll
    for (int n = 0; n < 9; ++n) {
      const ushort4 u0 = *(const ushort4*)(xb + (size_t)si[p][n][0] * 64);
      const ushort4 u1 = *(const ushort4*)(xb + (size_t)si[p][n][1] * 64);
      const ushort4 u2 = *(const ushort4*)(xb + (size_t)si[p][n][2] * 64);
      const ushort4 u3 = *(const ushort4*)(xb + (size_t)si[p][n][3] * 64);
      const float g0 = sg[p][n][0], g1 = sg[p][n][1], g2 = sg[p][n][2],
                  g3 = sg[p][n][3];
      float r0 = g0 * bf2f(u0.x);
      float r1 = g0 * bf2f(u0.y);
      float r2 = g0 * bf2f(u0.z);
      float r3 = g0 * bf2f(u0.w);
      r0 = fmaf(g1, bf2f(u1.x), r0); r1 = fmaf(g1, bf2f(u1.y), r1);
      r2 = fmaf(g1, bf2f(u1.z), r2); r3 = fmaf(g1, bf2f(u1.w), r3);
      r0 = fmaf(g2, bf2f(u2.x), r0); r1 = fmaf(g2, bf2f(u2.y), r1);
      r2 = fmaf(g2, bf2f(u2.z), r2); r3 = fmaf(g2, bf2f(u2.w), r3);
      r0 = fmaf(g3, bf2f(u3.x), r0); r1 = fmaf(g3, bf2f(u3.y), r1);
      r2 = fmaf(g3, bf2f(u3.z), r2); r3 = fmaf(g3, bf2f(u3.w), r3);
      ushort4 o;
      o.x = f2bf(r0); o.y = f2bf(r1); o.z = f2bf(r2); o.w = f2bf(r3);
      *(ushort4*)&A[p][n * 64 + ch4 * 4] = o;
    }
  }
  __syncthreads();

  {
    const int wv = t >> 6;
    const int lane = t & 63;
    const int l15 = lane & 15;
    const int quad = lane >> 4;
    const unsigned short* wbase = wtb + (((size_t)wv * 18) * 64 + lane) * 8;
    const unsigned short* arow = &A[l15][quad * 8];
    f32x4 acc = {0.f, 0.f, 0.f, 0.f};
#pragma unroll
    for (int kb = 0; kb < 18; ++kb) {
      short8 af = *(const short8*)(wbase + kb * 512);
      short8 bf = *(const short8*)(arow + kb * 32);
      acc = __builtin_amdgcn_mfma_f32_16x16x32_bf16(af, bf, acc, 0, 0, 0);
    }
#pragma unroll
    for (int r = 0; r < 4; ++r) {
      const int oc = wv * 16 + quad * 4 + r;
      const size_t idx = ((size_t)(b * Cin + oc)) * HW + hw0 + l15;
      out[idx] = x[idx] + acc[r];
    }
  }
}

}  // namespace

extern "C" void kernel_launch(void* const* d_in, const int* in_sizes, int n_in,
                              void* d_out, int out_size, void* d_ws,
                              size_t ws_size, hipStream_t stream) {
  const float* x = (const float*)d_in[0];
  const float* w1 = (const float*)d_in[1];
  const float* g1 = (const float*)d_in[2];
  const float* b1 = (const float*)d_in[3];
  const float* m1 = (const float*)d_in[4];
  const float* v1 = (const float*)d_in[5];
  const float* wdw = (const float*)d_in[6];
  const float* g2 = (const float*)d_in[7];
  const float* b2 = (const float*)d_in[8];
  const float* m2 = (const float*)d_in[9];
  const float* v2 = (const float*)d_in[10];
  const float* w2 = (const float*)d_in[11];
  const float* g3 = (const float*)d_in[12];
  const float* b3 = (const float*)d_in[13];
  const float* m3 = (const float*)d_in[14];
  const float* v3 = (const float*)d_in[15];
  const float* wout = (const float*)d_in[16];
  float* out = (float*)d_out;

  char* ws = (char*)d_ws;
  unsigned short* wtb = (unsigned short*)ws;           // 73,728 B (pad 81920)
  unsigned short* xT = (unsigned short*)(ws + 81920);  // 4,194,304 B
  float* offb = (float*)(ws + 81920 + 4194304);        // 2,359,296 B

  k_pre<<<656, 256, 0, stream>>>(x, xT, wout, wtb);
  k_off<<<512, 256, 0, stream>>>(xT, w1, g1, b1, m1, v1, wdw, g2, b2, m2, v2,
                                 w2, g3, b3, m3, v3, offb);
  k_main<<<2048, 256, 0, stream>>>(x, xT, offb, wtb, out);
}